// Round 1
// baseline (359.273 us; speedup 1.0000x reference)
//
#include <hip/hip_runtime.h>
#include <math.h>

#define Bn 8
#define Hn 48
#define Wn 48
#define Cn 256
#define HW (Hn*Wn)          // 2304
#define PIX (Bn*HW)         // 18432
#define RADF 6.0f

// ---------------------------------------------------------------------------
// K1: per-pixel MLP.  16 lanes per pixel; lane o computes output o of the
// 256->16 layer via float4 dot products, then tanh, then each lane contributes
// tt[o]*w to the 16->2 heads, reduced with width-16 xor shuffles.
// Writes: ws0[p] = (mean_x, mean_y, cv_raw0, cv_raw1); out_mean[p*2+{0,1}].
// ---------------------------------------------------------------------------
__global__ __launch_bounds__(256) void k1_mlp(
        const float* __restrict__ x,
        const float* __restrict__ map_w, const float* __restrict__ map_b,
        const float* __restrict__ mean_w, const float* __restrict__ mean_b,
        const float* __restrict__ cov_w,  const float* __restrict__ cov_b,
        float4* __restrict__ ws0, float* __restrict__ out_mean) {
    int tid = threadIdx.x;
    int o = tid & 15;
    int p = blockIdx.x * 16 + (tid >> 4);   // grid is exact: 18432/16 = 1152 blocks

    const float4* xr = (const float4*)(x + (size_t)p * Cn);
    const float4* wr = (const float4*)(map_w + (size_t)o * Cn);
    float acc = 0.f;
#pragma unroll 8
    for (int k = 0; k < Cn / 4; ++k) {
        float4 xv = xr[k], wv = wr[k];
        acc = fmaf(xv.x, wv.x, acc);
        acc = fmaf(xv.y, wv.y, acc);
        acc = fmaf(xv.z, wv.z, acc);
        acc = fmaf(xv.w, wv.w, acc);
    }
    float tt = tanhf(acc + map_b[o]);

    float m0 = tt * mean_w[o];
    float m1 = tt * mean_w[16 + o];
    float c0 = tt * cov_w[o];
    float c1 = tt * cov_w[16 + o];
#pragma unroll
    for (int off = 8; off; off >>= 1) {
        m0 += __shfl_xor(m0, off, 16);
        m1 += __shfl_xor(m1, off, 16);
        c0 += __shfl_xor(c0, off, 16);
        c1 += __shfl_xor(c1, off, 16);
    }
    if (o == 0) {
        int j = p % Wn;             // col -> coord[...,0]
        int i = (p / Wn) % Hn;      // row -> coord[...,1]
        float mx = m0 + mean_b[0] + (float)j;
        float my = m1 + mean_b[1] + (float)i;
        ws0[p] = make_float4(mx, my, c0 + cov_b[0], c1 + cov_b[1]);
        out_mean[(size_t)p * 2]     = mx;
        out_mean[(size_t)p * 2 + 1] = my;
    }
}

// ---------------------------------------------------------------------------
// K2: per-batch scalar mean/var over cv (4608 values), normalize, sigmoid*5
// +0.05, det, and precompute per-pixel Gaussian coefficients:
//   ws2[p] = (-0.5*log2e/cov0, -0.5*log2e/cov1, 1/(6.28*sqrt(det)), 0)
// One block per batch.
// ---------------------------------------------------------------------------
__global__ __launch_bounds__(256) void k2_norm(
        const float4* __restrict__ ws0,
        float4* __restrict__ ws2, float* __restrict__ out_det) {
    int b = blockIdx.x, tid = threadIdx.x;
    __shared__ float s1[256], s2[256];
    float sum = 0.f, sq = 0.f;
    for (int j = tid; j < HW; j += 256) {
        float4 r = ws0[b * HW + j];
        sum += r.z + r.w;
        sq = fmaf(r.z, r.z, sq);
        sq = fmaf(r.w, r.w, sq);
    }
    s1[tid] = sum; s2[tid] = sq;
    __syncthreads();
    for (int off = 128; off; off >>= 1) {
        if (tid < off) { s1[tid] += s1[tid + off]; s2[tid] += s2[tid + off]; }
        __syncthreads();
    }
    const float inv_n = 1.f / (2.f * HW);
    float mu   = s1[0] * inv_n;
    float var  = s2[0] * inv_n - mu * mu;
    float rstd = rsqrtf(var + 1e-5f);

    const float NL2E = -0.72134752044448169f;   // -0.5 * log2(e)
    for (int j = tid; j < HW; j += 256) {
        float4 r = ws0[b * HW + j];
        float z0 = (r.z - mu) * rstd;
        float z1 = (r.w - mu) * rstd;
        float cv0 = 5.f / (1.f + __expf(-z0)) + 0.05f;
        float cv1 = 5.f / (1.f + __expf(-z1)) + 0.05f;
        float det = cv0 * cv1;
        out_det[b * HW + j] = det;
        float inv_denom = 1.f / (6.28f * sqrtf(det));
        ws2[b * HW + j] = make_float4(NL2E / cv0, NL2E / cv1, inv_denom, 0.f);
    }
}

// ---------------------------------------------------------------------------
// K3: the heavy pass. One block (192 threads) per output pixel p=(b,i,j).
// Build separable tables ex[48], ey[48] (radius mask + 1/denom folded into
// ey), then each thread processes exactly 3 float4s of the 2304-element
// (h2,w2) plane: corr1 = fmaf(corr, ey[h2]*ex[w2], corr).
// Pure HBM-bound: 1 read + 1 write per element.
// ---------------------------------------------------------------------------
__global__ __launch_bounds__(192) void k3_mask(
        const float* __restrict__ corr,
        const float4* __restrict__ ws0, const float4* __restrict__ ws2,
        float* __restrict__ out) {
    int p = blockIdx.x;
    int tid = threadIdx.x;
    __shared__ float ex[Wn], ey[Hn];

    float4 m = ws0[p];   // (mean_x, mean_y, _, _) — same addr all lanes: broadcast
    float4 c = ws2[p];   // (k0, k1, inv_denom, _)
    if (tid < Wn) {
        float dx = (float)tid - m.x;
        ex[tid] = (fabsf(dx) <= RADF) ? exp2f(c.x * dx * dx) : 0.f;
    } else if (tid >= 64 && tid < 64 + Hn) {
        int h2 = tid - 64;
        float dy = (float)h2 - m.y;
        ey[h2] = (fabsf(dy) <= RADF) ? exp2f(c.y * dy * dy) * c.z : 0.f;
    }
    __syncthreads();

    const float4* src = (const float4*)(corr + (size_t)p * HW);
    float4*       dst = (float4*)(out + (size_t)p * HW);
#pragma unroll
    for (int it = 0; it < 3; ++it) {
        int i  = tid + it * 192;          // 0..575
        int h2 = i / 12;                  // 12 float4 per 48-wide row
        int w2 = (i - h2 * 12) * 4;
        float4 v = src[i];
        float eyv = ey[h2];
        v.x = fmaf(v.x, eyv * ex[w2],     v.x);
        v.y = fmaf(v.y, eyv * ex[w2 + 1], v.y);
        v.z = fmaf(v.z, eyv * ex[w2 + 2], v.z);
        v.w = fmaf(v.w, eyv * ex[w2 + 3], v.w);
        dst[i] = v;
    }
}

extern "C" void kernel_launch(void* const* d_in, const int* in_sizes, int n_in,
                              void* d_out, int out_size, void* d_ws, size_t ws_size,
                              hipStream_t stream) {
    const float* x      = (const float*)d_in[0];
    const float* corr   = (const float*)d_in[1];
    const float* map_w  = (const float*)d_in[2];
    const float* map_b  = (const float*)d_in[3];
    const float* mean_w = (const float*)d_in[4];
    const float* mean_b = (const float*)d_in[5];
    const float* cov_w  = (const float*)d_in[6];
    const float* cov_b  = (const float*)d_in[7];

    float* out       = (float*)d_out;
    float* out_corr1 = out;                                   // PIX*HW = 42,467,328
    float* out_mean  = out + (size_t)PIX * HW;                // PIX*2
    float* out_det   = out_mean + (size_t)PIX * 2;            // PIX

    float4* ws0 = (float4*)d_ws;        // PIX float4 = 294,912 B
    float4* ws2 = ws0 + PIX;            // PIX float4 = 294,912 B  (ws needs ~576 KiB)

    k1_mlp<<<PIX / 16, 256, 0, stream>>>(x, map_w, map_b, mean_w, mean_b,
                                         cov_w, cov_b, ws0, out_mean);
    k2_norm<<<Bn, 256, 0, stream>>>(ws0, ws2, out_det);
    k3_mask<<<PIX, 192, 0, stream>>>(corr, ws0, ws2, out_corr1);
}

// Round 3
// 346.356 us; speedup vs baseline: 1.0373x; 1.0373x over previous
//
#include <hip/hip_runtime.h>
#include <math.h>

#define Bn 8
#define Hn 48
#define Wn 48
#define Cn 256
#define HW (Hn*Wn)          // 2304
#define PIX (Bn*HW)         // 18432
#define RADF 6.0f
#define PPB 4               // pixels per k3 block

typedef float vfloat4 __attribute__((ext_vector_type(4)));  // native vec for nontemporal builtins

// ---------------------------------------------------------------------------
// K1: per-pixel MLP.  16 lanes per pixel; lane o computes output o of the
// 256->16 layer via float4 dot products, then tanh, then each lane contributes
// tt[o]*w to the 16->2 heads, reduced with width-16 xor shuffles.
// Writes: ws0[p] = (mean_x, mean_y, cv_raw0, cv_raw1); out_mean[p*2+{0,1}].
// ---------------------------------------------------------------------------
__global__ __launch_bounds__(256) void k1_mlp(
        const float* __restrict__ x,
        const float* __restrict__ map_w, const float* __restrict__ map_b,
        const float* __restrict__ mean_w, const float* __restrict__ mean_b,
        const float* __restrict__ cov_w,  const float* __restrict__ cov_b,
        float4* __restrict__ ws0, float* __restrict__ out_mean) {
    int tid = threadIdx.x;
    int o = tid & 15;
    int p = blockIdx.x * 16 + (tid >> 4);   // grid exact: 18432/16 = 1152 blocks

    const float4* xr = (const float4*)(x + (size_t)p * Cn);
    const float4* wr = (const float4*)(map_w + (size_t)o * Cn);
    float acc = 0.f;
#pragma unroll 8
    for (int k = 0; k < Cn / 4; ++k) {
        float4 xv = xr[k], wv = wr[k];
        acc = fmaf(xv.x, wv.x, acc);
        acc = fmaf(xv.y, wv.y, acc);
        acc = fmaf(xv.z, wv.z, acc);
        acc = fmaf(xv.w, wv.w, acc);
    }
    float tt = tanhf(acc + map_b[o]);

    float m0 = tt * mean_w[o];
    float m1 = tt * mean_w[16 + o];
    float c0 = tt * cov_w[o];
    float c1 = tt * cov_w[16 + o];
#pragma unroll
    for (int off = 8; off; off >>= 1) {
        m0 += __shfl_xor(m0, off, 16);
        m1 += __shfl_xor(m1, off, 16);
        c0 += __shfl_xor(c0, off, 16);
        c1 += __shfl_xor(c1, off, 16);
    }
    if (o == 0) {
        int j = p % Wn;             // col -> coord[...,0]
        int i = (p / Wn) % Hn;      // row -> coord[...,1]
        float mx = m0 + mean_b[0] + (float)j;
        float my = m1 + mean_b[1] + (float)i;
        ws0[p] = make_float4(mx, my, c0 + cov_b[0], c1 + cov_b[1]);
        out_mean[(size_t)p * 2]     = mx;
        out_mean[(size_t)p * 2 + 1] = my;
    }
}

// ---------------------------------------------------------------------------
// K2: per-batch scalar mean/var over cv (4608 values), normalize, sigmoid*5
// +0.05, det, and per-pixel Gaussian coefficients:
//   ws2[p] = (-0.5*log2e/cov0, -0.5*log2e/cov1, 1/(6.28*sqrt(det)), 0)
// ---------------------------------------------------------------------------
__global__ __launch_bounds__(256) void k2_norm(
        const float4* __restrict__ ws0,
        float4* __restrict__ ws2, float* __restrict__ out_det) {
    int b = blockIdx.x, tid = threadIdx.x;
    __shared__ float s1[256], s2[256];
    float sum = 0.f, sq = 0.f;
    for (int j = tid; j < HW; j += 256) {
        float4 r = ws0[b * HW + j];
        sum += r.z + r.w;
        sq = fmaf(r.z, r.z, sq);
        sq = fmaf(r.w, r.w, sq);
    }
    s1[tid] = sum; s2[tid] = sq;
    __syncthreads();
    for (int off = 128; off; off >>= 1) {
        if (tid < off) { s1[tid] += s1[tid + off]; s2[tid] += s2[tid + off]; }
        __syncthreads();
    }
    const float inv_n = 1.f / (2.f * HW);
    float mu   = s1[0] * inv_n;
    float var  = s2[0] * inv_n - mu * mu;
    float rstd = rsqrtf(var + 1e-5f);

    const float NL2E = -0.72134752044448169f;   // -0.5 * log2(e)
    for (int j = tid; j < HW; j += 256) {
        float4 r = ws0[b * HW + j];
        float z0 = (r.z - mu) * rstd;
        float z1 = (r.w - mu) * rstd;
        float cv0 = 5.f / (1.f + __expf(-z0)) + 0.05f;
        float cv1 = 5.f / (1.f + __expf(-z1)) + 0.05f;
        float det = cv0 * cv1;
        out_det[b * HW + j] = det;
        float inv_denom = 1.f / (6.28f * sqrtf(det));
        ws2[b * HW + j] = make_float4(NL2E / cv0, NL2E / cv1, inv_denom, 0.f);
    }
}

// ---------------------------------------------------------------------------
// K3: heavy streaming pass. 256 threads, PPB=4 pixels per block (grid 4608).
// Separable tables ex/ey per pixel in LDS (radius mask + 1/denom folded into
// ey); each thread does 9 float4: corr1 = fmaf(corr, ey*ex, corr).
// 576 float4/pixel = 9*64 -> a wave never straddles a pixel boundary, so the
// q index is wave-uniform and LDS reads are broadcast / <=2-way (free).
// Non-temporal load/store: corr is touch-once, skip L2 allocation.
// ---------------------------------------------------------------------------
__global__ __launch_bounds__(256) void k3_mask(
        const float* __restrict__ corr,
        const float4* __restrict__ ws0, const float4* __restrict__ ws2,
        float* __restrict__ out) {
    int bp = blockIdx.x * PPB;
    int tid = threadIdx.x;
    __shared__ float ex[PPB][Wn];
    __shared__ float ey[PPB][Hn];

    // 384 table entries, 256 threads -> 2 rounds
    for (int e = tid; e < PPB * 96; e += 256) {
        int q = e / 96, r = e - q * 96;
        float4 m = ws0[bp + q];
        float4 c = ws2[bp + q];
        if (r < Wn) {
            float dx = (float)r - m.x;
            ex[q][r] = (fabsf(dx) <= RADF) ? exp2f(c.x * dx * dx) : 0.f;
        } else {
            int h2 = r - Wn;
            float dy = (float)h2 - m.y;
            ey[q][h2] = (fabsf(dy) <= RADF) ? exp2f(c.y * dy * dy) * c.z : 0.f;
        }
    }
    __syncthreads();

    const vfloat4* src = (const vfloat4*)(corr + (size_t)bp * HW);
    vfloat4*       dst = (vfloat4*)(out + (size_t)bp * HW);
#pragma unroll
    for (int it = 0; it < 9; ++it) {
        int i  = it * 256 + tid;          // 0..2303 (PPB*576)
        int q  = i / 576;
        int r  = i - q * 576;
        int h2 = r / 12;                  // 12 float4 per 48-wide row
        int w2 = (r - h2 * 12) * 4;
        vfloat4 v = __builtin_nontemporal_load(&src[i]);
        float eyv = ey[q][h2];
        v.x = fmaf(v.x, eyv * ex[q][w2],     v.x);
        v.y = fmaf(v.y, eyv * ex[q][w2 + 1], v.y);
        v.z = fmaf(v.z, eyv * ex[q][w2 + 2], v.z);
        v.w = fmaf(v.w, eyv * ex[q][w2 + 3], v.w);
        __builtin_nontemporal_store(v, &dst[i]);
    }
}

extern "C" void kernel_launch(void* const* d_in, const int* in_sizes, int n_in,
                              void* d_out, int out_size, void* d_ws, size_t ws_size,
                              hipStream_t stream) {
    const float* x      = (const float*)d_in[0];
    const float* corr   = (const float*)d_in[1];
    const float* map_w  = (const float*)d_in[2];
    const float* map_b  = (const float*)d_in[3];
    const float* mean_w = (const float*)d_in[4];
    const float* mean_b = (const float*)d_in[5];
    const float* cov_w  = (const float*)d_in[6];
    const float* cov_b  = (const float*)d_in[7];

    float* out       = (float*)d_out;
    float* out_corr1 = out;                                   // PIX*HW
    float* out_mean  = out + (size_t)PIX * HW;                // PIX*2
    float* out_det   = out_mean + (size_t)PIX * 2;            // PIX

    float4* ws0 = (float4*)d_ws;        // PIX float4
    float4* ws2 = ws0 + PIX;            // PIX float4

    k1_mlp<<<PIX / 16, 256, 0, stream>>>(x, map_w, map_b, mean_w, mean_b,
                                         cov_w, cov_b, ws0, out_mean);
    k2_norm<<<Bn, 256, 0, stream>>>(ws0, ws2, out_det);
    k3_mask<<<PIX / PPB, 256, 0, stream>>>(corr, ws0, ws2, out_corr1);
}